// Round 3
// baseline (2948.684 us; speedup 1.0000x reference)
//
#include <hip/hip_runtime.h>
#include <hip/hip_bf16.h>
#include <math.h>

__device__ __forceinline__ void atomicMaxFloat(float* addr, float val) {
    val += 0.0f;  // canonicalize -0.0 -> +0.0 so the signed-int path is safe
    if (val >= 0.f) atomicMax((int*)addr, __float_as_int(val));
    else            atomicMin((unsigned int*)addr, (unsigned int)__float_as_int(val));
}

// ---------------- prep: fold b_gat into fusion bias ----------------
__global__ void prep_kernel(const float* __restrict__ b_gat,
                            const float* __restrict__ W_fus, const float* __restrict__ b_fus,
                            float* __restrict__ bfus2) {
    int t = threadIdx.x;  // 128
    float acc = b_fus[t];
    for (int k = 0; k < 128; k++)
        acc += b_gat[k] * W_fus[t * 256 + 128 + k];
    bfus2[t] = acc;
}

// ------- GEMM: C[n,128] = A[n,128] @ W[:, off:off+128]^T (+bias) (+=) -------
template <bool ACCUM>
__global__ __launch_bounds__(256) void gemm128(
    const float* __restrict__ A, const float* __restrict__ W,
    int w_stride, int w_off, const float* __restrict__ bias,
    float* __restrict__ C, int n) {
    __shared__ float Alds[32 * 132];
    __shared__ float Wlds[32 * 128];  // Wt[kk][o] for one 32-wide K tile
    const int t = threadIdx.x;
    const int row0 = blockIdx.x * 32;

    for (int i = 0; i < 16; i++) {
        int idx = i * 256 + t;
        int r = idx >> 7, k = idx & 127;
        int row = row0 + r;
        Alds[r * 132 + k] = (row < n) ? A[(size_t)row * 128 + k] : 0.f;
    }

    const int rg = t >> 5, cg = t & 31;
    float acc[4][4] = {};

    for (int kt = 0; kt < 4; kt++) {
        __syncthreads();  // Wlds reuse (also orders A staging before first compute)
        for (int i = 0; i < 16; i++) {
            int idx = i * 256 + t;
            int kk = idx >> 7, o = idx & 127;
            Wlds[kk * 128 + o] = W[o * w_stride + w_off + kt * 32 + kk];
        }
        __syncthreads();

        const float* Ab = &Alds[(rg * 4) * 132 + kt * 32];
        for (int k4 = 0; k4 < 8; k4++) {
            float4 av0 = *(const float4*)&Ab[0 * 132 + k4 * 4];
            float4 av1 = *(const float4*)&Ab[1 * 132 + k4 * 4];
            float4 av2 = *(const float4*)&Ab[2 * 132 + k4 * 4];
            float4 av3 = *(const float4*)&Ab[3 * 132 + k4 * 4];
            float a_[4][4] = {{av0.x, av0.y, av0.z, av0.w},
                              {av1.x, av1.y, av1.z, av1.w},
                              {av2.x, av2.y, av2.z, av2.w},
                              {av3.x, av3.y, av3.z, av3.w}};
#pragma unroll
            for (int kk = 0; kk < 4; kk++) {
                float4 wv = *(const float4*)&Wlds[(k4 * 4 + kk) * 128 + cg * 4];
#pragma unroll
                for (int r = 0; r < 4; r++) {
                    float a = a_[r][kk];
                    acc[r][0] += a * wv.x;
                    acc[r][1] += a * wv.y;
                    acc[r][2] += a * wv.z;
                    acc[r][3] += a * wv.w;
                }
            }
        }
    }
#pragma unroll
    for (int r = 0; r < 4; r++) {
        int row = row0 + rg * 4 + r;
        if (row >= n) continue;
        float4 o;
        o.x = acc[r][0]; o.y = acc[r][1]; o.z = acc[r][2]; o.w = acc[r][3];
        if (bias) {
            o.x += bias[cg * 4 + 0]; o.y += bias[cg * 4 + 1];
            o.z += bias[cg * 4 + 2]; o.w += bias[cg * 4 + 3];
        }
        float* cp = &C[(size_t)row * 128 + cg * 4];
        if (ACCUM) {
            float4 old = *(const float4*)cp;
            o.x += old.x; o.y += old.y; o.z += old.z; o.w += old.w;
        }
        *(float4*)cp = o;
    }
}

// ---------------- degree / dinv ----------------
__global__ void deg_kernel(const int* __restrict__ col, float* __restrict__ deg, int E, int N) {
    int i = blockIdx.x * 256 + threadIdx.x;
    if (i < E) {
        int c = col[i];
        if ((unsigned)c < (unsigned)N) atomicAdd(&deg[c], 1.0f);
    }
}
__global__ void dinv_kernel(const float* __restrict__ deg, float* __restrict__ dinv, int N) {
    int i = blockIdx.x * 256 + threadIdx.x;
    if (i < N) {
        float d = deg[i];
        dinv[i] = d > 0.f ? 1.0f / sqrtf(d) : 0.0f;
    }
}

// ---------------- E8 scatter: agg[row] += h[col] * dinv[row]*dinv[col] ----------
__global__ __launch_bounds__(256) void e8_scatter(
    const int* __restrict__ row, const int* __restrict__ col,
    const float* __restrict__ dinv, const float* __restrict__ h,
    float* __restrict__ agg, int E, int N) {
    int e = blockIdx.x * 4 + (threadIdx.x >> 6);
    int lane = threadIdx.x & 63;
    if (e >= E) return;
    int r = row[e], c = col[e];
    if ((unsigned)r >= (unsigned)N || (unsigned)c >= (unsigned)N) return;
    float val = dinv[r] * dinv[c];
    if (val == 0.f) return;
    const float* hc = &h[(size_t)c * 128];
    float* ar = &agg[(size_t)r * 128];
    atomicAdd(&ar[lane], hc[lane] * val);
    atomicAdd(&ar[lane + 64], hc[lane + 64] * val);
}

// ---------------- attention coefficients ----------------
__global__ void att_kernel(const float* __restrict__ g, const float* __restrict__ att_src,
                           const float* __restrict__ att_dst,
                           float* __restrict__ a_src, float* __restrict__ a_dst, int N) {
    int tid = blockIdx.x * 256 + threadIdx.x;
    if (tid >= N * 4) return;
    int n = tid >> 2, hd = tid & 3;
    const float* gr = &g[(size_t)n * 128 + hd * 32];
    const float* as = att_src + hd * 32;
    const float* ad = att_dst + hd * 32;
    float s = 0.f, d = 0.f;
    for (int c = 0; c < 32; c += 4) {
        float4 gv = *(const float4*)&gr[c];
        float4 sv = *(const float4*)&as[c];
        float4 dv = *(const float4*)&ad[c];
        s += gv.x * sv.x + gv.y * sv.y + gv.z * sv.z + gv.w * sv.w;
        d += gv.x * dv.x + gv.y * dv.y + gv.z * dv.z + gv.w * dv.w;
    }
    a_src[tid] = s;
    a_dst[tid] = d;
}

// ---------------- GAT scatter max ----------------
__global__ void gat_amax(const int* __restrict__ row, const int* __restrict__ col,
                         const float* __restrict__ a_src, const float* __restrict__ a_dst,
                         float* __restrict__ m, int E, int N) {
    int tid = blockIdx.x * 256 + threadIdx.x;
    int i = tid >> 2, hd = tid & 3;
    int M = E + N;
    if (i >= M) return;
    int s, d;
    if (i < E) {
        s = row[i]; d = col[i];
        if ((unsigned)s >= (unsigned)N || (unsigned)d >= (unsigned)N) return;
    } else { s = d = i - E; }
    float e = a_src[s * 4 + hd] + a_dst[d * 4 + hd];
    e = e > 0.f ? e : 0.2f * e;
    atomicMaxFloat(&m[d * 4 + hd], e);
}

// ---------------- GAT scatter exp-sum ----------------
__global__ void gat_ssum(const int* __restrict__ row, const int* __restrict__ col,
                         const float* __restrict__ a_src, const float* __restrict__ a_dst,
                         const float* __restrict__ m, float* __restrict__ sbuf, int E, int N) {
    int tid = blockIdx.x * 256 + threadIdx.x;
    int i = tid >> 2, hd = tid & 3;
    int M = E + N;
    if (i >= M) return;
    int s, d;
    if (i < E) {
        s = row[i]; d = col[i];
        if ((unsigned)s >= (unsigned)N || (unsigned)d >= (unsigned)N) return;
    } else { s = d = i - E; }
    float e = a_src[s * 4 + hd] + a_dst[d * 4 + hd];
    e = e > 0.f ? e : 0.2f * e;
    atomicAdd(&sbuf[d * 4 + hd], expf(e - m[d * 4 + hd]));
}

// ---------------- GAT message scatter ----------------
__global__ __launch_bounds__(256) void gat_msg(
    const int* __restrict__ row, const int* __restrict__ col,
    const float* __restrict__ a_src, const float* __restrict__ a_dst,
    const float* __restrict__ m, const float* __restrict__ sbuf,
    const float* __restrict__ g, float* __restrict__ xg, int E, int N) {
    int i = blockIdx.x * 4 + (threadIdx.x >> 6);
    int lane = threadIdx.x & 63;
    int M = E + N;
    if (i >= M) return;
    int s, d;
    if (i < E) {
        s = row[i]; d = col[i];
        if ((unsigned)s >= (unsigned)N || (unsigned)d >= (unsigned)N) return;
    } else { s = d = i - E; }
#pragma unroll
    for (int j = 0; j < 2; j++) {
        int f = lane + 64 * j;
        int hd = f >> 5;
        float e = a_src[s * 4 + hd] + a_dst[d * 4 + hd];
        e = e > 0.f ? e : 0.2f * e;
        float alpha = expf(e - m[d * 4 + hd]) / (sbuf[d * 4 + hd] + 1e-16f);
        atomicAdd(&xg[(size_t)d * 128 + f], g[(size_t)s * 128 + f] * alpha);
    }
}

// ---------------- fusion residual + LayerNorm + ReLU ----------------
__global__ __launch_bounds__(128) void ln_kernel(
    const float* __restrict__ f, const float* __restrict__ h,
    const float* __restrict__ gamma, const float* __restrict__ beta,
    float* __restrict__ z, int N) {
    __shared__ float red[128];
    __shared__ float red2[128];
    int nidx = blockIdx.x;
    int t = threadIdx.x;
    float v = f[(size_t)nidx * 128 + t] + h[(size_t)nidx * 128 + t];
    red[t] = v;
    red2[t] = v * v;
    __syncthreads();
    for (int s = 64; s > 0; s >>= 1) {
        if (t < s) { red[t] += red[t + s]; red2[t] += red2[t + s]; }
        __syncthreads();
    }
    float mu = red[0] * (1.f / 128.f);
    float var = red2[0] * (1.f / 128.f) - mu * mu;
    float inv = rsqrtf(var + 1e-5f);
    float zz = (v - mu) * inv * gamma[t] + beta[t];
    z[(size_t)nidx * 128 + t] = zz > 0.f ? zz : 0.f;
}

// ---------------- readout MLP + sigmoid (fp32 output!) ----------------
__global__ __launch_bounds__(256) void readout_kernel(
    const float* __restrict__ z, const float* __restrict__ W1, const float* __restrict__ b1,
    const float* __restrict__ W2, const float* __restrict__ b2,
    float* __restrict__ out, int N) {
    int n = blockIdx.x * 4 + (threadIdx.x >> 6);
    int lane = threadIdx.x & 63;
    if (n >= N) return;
    const float* zr = &z[(size_t)n * 128];
    const float* w1 = W1 + lane * 128;
    float acc = 0.f;
    for (int k = 0; k < 128; k += 4) {
        float4 zv = *(const float4*)&zr[k];
        float4 wv = *(const float4*)&w1[k];
        acc += zv.x * wv.x + zv.y * wv.y + zv.z * wv.z + zv.w * wv.w;
    }
    acc += b1[lane];
    acc = acc > 0.f ? acc : 0.f;
    float p = acc * W2[lane];
    for (int off = 32; off > 0; off >>= 1) p += __shfl_down(p, off);
    if (lane == 0) {
        float o = p + b2[0];
        out[n] = 1.f / (1.f + expf(-o));
    }
}

extern "C" void kernel_launch(void* const* d_in, const int* in_sizes, int n_in,
                              void* d_out, int out_size, void* d_ws, size_t ws_size,
                              hipStream_t stream) {
    const float* x     = (const float*)d_in[0];
    const int*   ei    = (const int*)d_in[1];
    const float* W_emb = (const float*)d_in[2];
    const float* b_emb = (const float*)d_in[3];
    const float* W_e8  = (const float*)d_in[4];
    const float* W_gat = (const float*)d_in[5];
    const float* att_s = (const float*)d_in[6];
    const float* att_d = (const float*)d_in[7];
    const float* b_gat = (const float*)d_in[8];
    const float* W_fus = (const float*)d_in[9];
    const float* b_fus = (const float*)d_in[10];
    const float* gamma = (const float*)d_in[11];
    const float* beta  = (const float*)d_in[12];
    const float* W_r1  = (const float*)d_in[13];
    const float* b_r1  = (const float*)d_in[14];
    const float* W_r2  = (const float*)d_in[15];
    const float* b_r2  = (const float*)d_in[16];

    const int N = in_sizes[0] / 128;
    const int E = in_sizes[1] / 2;
    const int M = E + N;
    const int* rowp = ei;
    const int* colp = ei + E;

    float* ws = (float*)d_ws;
    const size_t NF = (size_t)N * 128;
    float* B_h   = ws;            // h (residual), live until LN
    float* B_agg = B_h + NF;      // agg -> x_gat
    float* B_e8  = B_agg + NF;    // x_e8 -> z
    float* B_g   = B_e8 + NF;     // g -> f
    float* deg   = B_g + NF;
    float* dinv  = deg + N;
    float* a_src = dinv + N;
    float* a_dst = a_src + (size_t)4 * N;
    float* mbuf  = a_dst + (size_t)4 * N;
    float* sbuf  = mbuf + (size_t)4 * N;
    float* bfus2 = sbuf + (size_t)4 * N;

    // prep + zero init
    prep_kernel<<<1, 128, 0, stream>>>(b_gat, W_fus, b_fus, bfus2);
    hipMemsetAsync(deg, 0, (size_t)N * 4, stream);
    hipMemsetAsync(B_agg, 0, NF * 4, stream);
    hipMemsetAsync(mbuf, 0xFF, (size_t)4 * N * 4, stream);  // NaN bits; any real update replaces
    hipMemsetAsync(sbuf, 0, (size_t)4 * N * 4, stream);

    // h = x @ W_emb^T + b_emb
    gemm128<false><<<(N + 31) / 32, 256, 0, stream>>>(x, W_emb, 128, 0, b_emb, B_h, N);

    // degree / dinv
    deg_kernel<<<(E + 255) / 256, 256, 0, stream>>>(colp, deg, E, N);
    dinv_kernel<<<(N + 255) / 256, 256, 0, stream>>>(deg, dinv, N);

    // E8 aggregate + linear
    e8_scatter<<<(E + 3) / 4, 256, 0, stream>>>(rowp, colp, dinv, B_h, B_agg, E, N);
    gemm128<false><<<(N + 31) / 32, 256, 0, stream>>>(B_agg, W_e8, 128, 0, nullptr, B_e8, N);

    // GAT
    gemm128<false><<<(N + 31) / 32, 256, 0, stream>>>(B_h, W_gat, 128, 0, nullptr, B_g, N);
    att_kernel<<<(4 * N + 255) / 256, 256, 0, stream>>>(B_g, att_s, att_d, a_src, a_dst, N);
    gat_amax<<<(4 * M + 255) / 256, 256, 0, stream>>>(rowp, colp, a_src, a_dst, mbuf, E, N);
    gat_ssum<<<(4 * M + 255) / 256, 256, 0, stream>>>(rowp, colp, a_src, a_dst, mbuf, sbuf, E, N);
    hipMemsetAsync(B_agg, 0, NF * 4, stream);  // reuse as x_gat accumulator
    gat_msg<<<(M + 3) / 4, 256, 0, stream>>>(rowp, colp, a_src, a_dst, mbuf, sbuf, B_g, B_agg, E, N);

    // fusion: f = x_e8 @ Wf[:, :128]^T + (b_fus + Wf[:,128:]·b_gat) ; f += x_gat @ Wf[:,128:]^T
    gemm128<false><<<(N + 31) / 32, 256, 0, stream>>>(B_e8, W_fus, 256, 0, bfus2, B_g, N);
    gemm128<true><<<(N + 31) / 32, 256, 0, stream>>>(B_agg, W_fus, 256, 128, nullptr, B_g, N);

    // residual + LayerNorm + ReLU -> z (reuse B_e8)
    ln_kernel<<<N, 128, 0, stream>>>(B_g, B_h, gamma, beta, B_e8, N);

    // readout (f32 out — this was the round-2 bug)
    readout_kernel<<<(N + 3) / 4, 256, 0, stream>>>(B_e8, W_r1, b_r1, W_r2, b_r2,
                                                    (float*)d_out, N);
}

// Round 4
// 2039.938 us; speedup vs baseline: 1.4455x; 1.4455x over previous
//
#include <hip/hip_runtime.h>
#include <hip/hip_bf16.h>
#include <math.h>

#define SCAN_TILE 1024

// ---------------- prep: fold b_gat into fusion bias ----------------
__global__ void prep_kernel(const float* __restrict__ b_gat,
                            const float* __restrict__ W_fus, const float* __restrict__ b_fus,
                            float* __restrict__ bfus2) {
    int t = threadIdx.x;  // 128
    float acc = b_fus[t];
    for (int k = 0; k < 128; k++)
        acc += b_gat[k] * W_fus[t * 256 + 128 + k];
    bfus2[t] = acc;
}

// ---------------- CSR build: count ----------------
__global__ void count_kernel(const int* __restrict__ row, const int* __restrict__ col,
                             int* __restrict__ degs, int E, int N) {
    int e = blockIdx.x * 256 + threadIdx.x;
    if (e >= E) return;
    atomicAdd(&degs[col[e]], 1);       // dst counts (== reference deg)
    atomicAdd(&degs[N + row[e]], 1);   // src counts
}

// ---------------- CSR build: scan (3 kernels) ----------------
__global__ void scan_reduce(const int* __restrict__ degs, int* __restrict__ part, int total) {
    int b = blockIdx.x, t = threadIdx.x;  // 256 threads
    int base = b * SCAN_TILE + t * 4;
    int s = 0;
#pragma unroll
    for (int j = 0; j < 4; j++) { int i = base + j; if (i < total) s += degs[i]; }
    __shared__ int red[256];
    red[t] = s; __syncthreads();
    for (int st = 128; st > 0; st >>= 1) {
        if (t < st) red[t] += red[t + st];
        __syncthreads();
    }
    if (t == 0) part[b] = red[0];
}

__global__ void scan_partials(int* __restrict__ part, int P) {
    if (threadIdx.x == 0) {
        int run = 0;
        for (int i = 0; i < P; i++) { int v = part[i]; part[i] = run; run += v; }
    }
}

__global__ void scan_write(const int* __restrict__ degs, const int* __restrict__ part,
                           int* __restrict__ row_ptr, int* __restrict__ cursor,
                           float* __restrict__ dinv, int total, int N) {
    int b = blockIdx.x, t = threadIdx.x;  // 256
    int base = b * SCAN_TILE + t * 4;
    int v[4]; int s = 0;
#pragma unroll
    for (int j = 0; j < 4; j++) { int i = base + j; v[j] = (i < total) ? degs[i] : 0; s += v[j]; }
    __shared__ int bufA[256], bufB[256];
    bufA[t] = s; __syncthreads();
    int* src = bufA; int* dst = bufB;
    for (int off = 1; off < 256; off <<= 1) {
        int x = src[t];
        if (t >= off) x += src[t - off];
        dst[t] = x; __syncthreads();
        int* tp = src; src = dst; dst = tp;
    }
    int excl = src[t] - s;             // exclusive prefix of this thread's 4-chunk
    int run = part[b] + excl;
#pragma unroll
    for (int j = 0; j < 4; j++) {
        int i = base + j;
        if (i < total) {
            row_ptr[i] = run;
            cursor[i] = run;
            if (i < N) dinv[i] = v[j] > 0 ? rsqrtf((float)v[j]) : 0.0f;
            run += v[j];
        }
    }
}

// ---------------- CSR build: fill ----------------
__global__ void fill_kernel(const int* __restrict__ row, const int* __restrict__ col,
                            int* __restrict__ cursor, int* __restrict__ adj, int E, int N) {
    int e = blockIdx.x * 256 + threadIdx.x;
    if (e >= E) return;
    int r = row[e], c = col[e];
    int p1 = atomicAdd(&cursor[c], 1);      adj[p1] = r;  // dst-CSR: stores src
    int p2 = atomicAdd(&cursor[N + r], 1);  adj[p2] = c;  // src-CSR: stores dst
}

// ------- GEMM: C[n,128] = A[n,128] @ W[:, off:off+128]^T (+bias) (+=) -------
template <bool ACCUM>
__global__ __launch_bounds__(256) void gemm128(
    const float* __restrict__ A, const float* __restrict__ W,
    int w_stride, int w_off, const float* __restrict__ bias,
    float* __restrict__ C, int n) {
    __shared__ float Alds[32 * 132];
    __shared__ float Wlds[32 * 128];
    const int t = threadIdx.x;
    const int row0 = blockIdx.x * 32;

    for (int i = 0; i < 16; i++) {
        int idx = i * 256 + t;
        int r = idx >> 7, k = idx & 127;
        int row = row0 + r;
        Alds[r * 132 + k] = (row < n) ? A[(size_t)row * 128 + k] : 0.f;
    }

    const int rg = t >> 5, cg = t & 31;
    float acc[4][4] = {};

    for (int kt = 0; kt < 4; kt++) {
        __syncthreads();
        for (int i = 0; i < 16; i++) {
            int idx = i * 256 + t;
            int kk = idx >> 7, o = idx & 127;
            Wlds[kk * 128 + o] = W[o * w_stride + w_off + kt * 32 + kk];
        }
        __syncthreads();

        const float* Ab = &Alds[(rg * 4) * 132 + kt * 32];
        for (int k4 = 0; k4 < 8; k4++) {
            float4 av0 = *(const float4*)&Ab[0 * 132 + k4 * 4];
            float4 av1 = *(const float4*)&Ab[1 * 132 + k4 * 4];
            float4 av2 = *(const float4*)&Ab[2 * 132 + k4 * 4];
            float4 av3 = *(const float4*)&Ab[3 * 132 + k4 * 4];
            float a_[4][4] = {{av0.x, av0.y, av0.z, av0.w},
                              {av1.x, av1.y, av1.z, av1.w},
                              {av2.x, av2.y, av2.z, av2.w},
                              {av3.x, av3.y, av3.z, av3.w}};
#pragma unroll
            for (int kk = 0; kk < 4; kk++) {
                float4 wv = *(const float4*)&Wlds[(k4 * 4 + kk) * 128 + cg * 4];
#pragma unroll
                for (int r = 0; r < 4; r++) {
                    float a = a_[r][kk];
                    acc[r][0] += a * wv.x;
                    acc[r][1] += a * wv.y;
                    acc[r][2] += a * wv.z;
                    acc[r][3] += a * wv.w;
                }
            }
        }
    }
#pragma unroll
    for (int r = 0; r < 4; r++) {
        int row = row0 + rg * 4 + r;
        if (row >= n) continue;
        float4 o;
        o.x = acc[r][0]; o.y = acc[r][1]; o.z = acc[r][2]; o.w = acc[r][3];
        if (bias) {
            o.x += bias[cg * 4 + 0]; o.y += bias[cg * 4 + 1];
            o.z += bias[cg * 4 + 2]; o.w += bias[cg * 4 + 3];
        }
        float* cp = &C[(size_t)row * 128 + cg * 4];
        if (ACCUM) {
            float4 old = *(const float4*)cp;
            o.x += old.x; o.y += old.y; o.z += old.z; o.w += old.w;
        }
        *(float4*)cp = o;
    }
}

// ------- E8 gather: agg[r] = dinv[r] * sum_{c in srcCSR[r]} h[c]*dinv[c] -------
__global__ __launch_bounds__(256) void e8_gather(
    const int* __restrict__ row_ptr, const int* __restrict__ degs,
    const int* __restrict__ adj, const float* __restrict__ dinv,
    const float* __restrict__ h, float* __restrict__ agg, int N) {
    int r = blockIdx.x * 4 + (threadIdx.x >> 6);
    int lane = threadIdx.x & 63;
    if (r >= N) return;
    int start = row_ptr[N + r], cnt = degs[N + r];
    float acc0 = 0.f, acc1 = 0.f;
    for (int k = 0; k < cnt; k++) {
        int c = adj[start + k];
        float vc = dinv[c];
        const float* hc = &h[(size_t)c * 128];
        acc0 += hc[lane] * vc;
        acc1 += hc[lane + 64] * vc;
    }
    float dr = dinv[r];
    agg[(size_t)r * 128 + lane]      = acc0 * dr;
    agg[(size_t)r * 128 + lane + 64] = acc1 * dr;
}

// ---------------- attention coefficients ----------------
__global__ void att_kernel(const float* __restrict__ g, const float* __restrict__ att_src,
                           const float* __restrict__ att_dst,
                           float* __restrict__ a_src, float* __restrict__ a_dst, int N) {
    int tid = blockIdx.x * 256 + threadIdx.x;
    if (tid >= N * 4) return;
    int n = tid >> 2, hd = tid & 3;
    const float* gr = &g[(size_t)n * 128 + hd * 32];
    const float* as = att_src + hd * 32;
    const float* ad = att_dst + hd * 32;
    float s = 0.f, d = 0.f;
    for (int c = 0; c < 32; c += 4) {
        float4 gv = *(const float4*)&gr[c];
        float4 sv = *(const float4*)&as[c];
        float4 dv = *(const float4*)&ad[c];
        s += gv.x * sv.x + gv.y * sv.y + gv.z * sv.z + gv.w * sv.w;
        d += gv.x * dv.x + gv.y * dv.y + gv.z * dv.z + gv.w * dv.w;
    }
    a_src[tid] = s;
    a_dst[tid] = d;
}

// ------- GAT fused: online softmax over dst-CSR (+implicit self-loop) -------
__global__ __launch_bounds__(256) void gat_gather(
    const int* __restrict__ row_ptr, const int* __restrict__ degs,
    const int* __restrict__ adj, const float* __restrict__ a_src,
    const float* __restrict__ a_dst, const float* __restrict__ g,
    float* __restrict__ xg, int N) {
    int d = blockIdx.x * 4 + (threadIdx.x >> 6);
    int lane = threadIdx.x & 63;
    if (d >= N) return;
    int hd0 = lane >> 5;       // 0 or 1
    int hd1 = hd0 + 2;         // 2 or 3
    int f0 = lane, f1 = lane + 64;

    float ad0 = a_dst[d * 4 + hd0], ad1 = a_dst[d * 4 + hd1];

    // self-loop seeds the online softmax
    float e0 = a_src[d * 4 + hd0] + ad0; e0 = e0 > 0.f ? e0 : 0.2f * e0;
    float e1 = a_src[d * 4 + hd1] + ad1; e1 = e1 > 0.f ? e1 : 0.2f * e1;
    float m0 = e0, l0 = 1.f, acc0 = g[(size_t)d * 128 + f0];
    float m1 = e1, l1 = 1.f, acc1 = g[(size_t)d * 128 + f1];

    int start = row_ptr[d], cnt = degs[d];
    for (int k = 0; k < cnt; k++) {
        int s = adj[start + k];
        float t0 = a_src[s * 4 + hd0] + ad0; t0 = t0 > 0.f ? t0 : 0.2f * t0;
        float t1 = a_src[s * 4 + hd1] + ad1; t1 = t1 > 0.f ? t1 : 0.2f * t1;
        const float* gs = &g[(size_t)s * 128];
        float g0 = gs[f0], g1 = gs[f1];
        float mn0 = fmaxf(m0, t0);
        float sc0 = __expf(m0 - mn0), w0 = __expf(t0 - mn0);
        acc0 = acc0 * sc0 + w0 * g0; l0 = l0 * sc0 + w0; m0 = mn0;
        float mn1 = fmaxf(m1, t1);
        float sc1 = __expf(m1 - mn1), w1 = __expf(t1 - mn1);
        acc1 = acc1 * sc1 + w1 * g1; l1 = l1 * sc1 + w1; m1 = mn1;
    }
    xg[(size_t)d * 128 + f0] = acc0 / l0;
    xg[(size_t)d * 128 + f1] = acc1 / l1;
}

// ---------------- fusion residual + LayerNorm + ReLU ----------------
__global__ __launch_bounds__(128) void ln_kernel(
    const float* __restrict__ f, const float* __restrict__ h,
    const float* __restrict__ gamma, const float* __restrict__ beta,
    float* __restrict__ z, int N) {
    __shared__ float red[128];
    __shared__ float red2[128];
    int nidx = blockIdx.x;
    int t = threadIdx.x;
    float v = f[(size_t)nidx * 128 + t] + h[(size_t)nidx * 128 + t];
    red[t] = v;
    red2[t] = v * v;
    __syncthreads();
    for (int s = 64; s > 0; s >>= 1) {
        if (t < s) { red[t] += red[t + s]; red2[t] += red2[t + s]; }
        __syncthreads();
    }
    float mu = red[0] * (1.f / 128.f);
    float var = red2[0] * (1.f / 128.f) - mu * mu;
    float inv = rsqrtf(var + 1e-5f);
    float zz = (v - mu) * inv * gamma[t] + beta[t];
    z[(size_t)nidx * 128 + t] = zz > 0.f ? zz : 0.f;
}

// ---------------- readout MLP + sigmoid (fp32 output) ----------------
__global__ __launch_bounds__(256) void readout_kernel(
    const float* __restrict__ z, const float* __restrict__ W1, const float* __restrict__ b1,
    const float* __restrict__ W2, const float* __restrict__ b2,
    float* __restrict__ out, int N) {
    int n = blockIdx.x * 4 + (threadIdx.x >> 6);
    int lane = threadIdx.x & 63;
    if (n >= N) return;
    const float* zr = &z[(size_t)n * 128];
    const float* w1 = W1 + lane * 128;
    float acc = 0.f;
    for (int k = 0; k < 128; k += 4) {
        float4 zv = *(const float4*)&zr[k];
        float4 wv = *(const float4*)&w1[k];
        acc += zv.x * wv.x + zv.y * wv.y + zv.z * wv.z + zv.w * wv.w;
    }
    acc += b1[lane];
    acc = acc > 0.f ? acc : 0.f;
    float p = acc * W2[lane];
    for (int off = 32; off > 0; off >>= 1) p += __shfl_down(p, off);
    if (lane == 0) {
        float o = p + b2[0];
        out[n] = 1.f / (1.f + expf(-o));
    }
}

extern "C" void kernel_launch(void* const* d_in, const int* in_sizes, int n_in,
                              void* d_out, int out_size, void* d_ws, size_t ws_size,
                              hipStream_t stream) {
    const float* x     = (const float*)d_in[0];
    const int*   ei    = (const int*)d_in[1];
    const float* W_emb = (const float*)d_in[2];
    const float* b_emb = (const float*)d_in[3];
    const float* W_e8  = (const float*)d_in[4];
    const float* W_gat = (const float*)d_in[5];
    const float* att_s = (const float*)d_in[6];
    const float* att_d = (const float*)d_in[7];
    const float* b_gat = (const float*)d_in[8];
    const float* W_fus = (const float*)d_in[9];
    const float* b_fus = (const float*)d_in[10];
    const float* gamma = (const float*)d_in[11];
    const float* beta  = (const float*)d_in[12];
    const float* W_r1  = (const float*)d_in[13];
    const float* b_r1  = (const float*)d_in[14];
    const float* W_r2  = (const float*)d_in[15];
    const float* b_r2  = (const float*)d_in[16];

    const int N = in_sizes[0] / 128;
    const int E = in_sizes[1] / 2;
    const int* rowp = ei;
    const int* colp = ei + E;
    const int total = 2 * N;
    const int P = (total + SCAN_TILE - 1) / SCAN_TILE;

    const size_t NF = (size_t)N * 128;
    float* ws = (float*)d_ws;
    float* B_h   = ws;            // h (residual), live until LN
    float* B_agg = B_h + NF;      // e8 agg, then x_gat
    float* B_e8  = B_agg + NF;    // x_e8, then z
    float* B_g   = B_e8 + NF;     // g, then f
    float* dinv  = B_g + NF;
    float* a_src = dinv + N;
    float* a_dst = a_src + (size_t)4 * N;
    float* bfus2 = a_dst + (size_t)4 * N;
    int* degs    = (int*)(bfus2 + 128);
    int* row_ptr = degs + total;
    int* cursor  = row_ptr + total;
    int* part    = cursor + total;
    int* adj     = part + 1024;       // 2E ints

    // --- prep + CSR build ---
    prep_kernel<<<1, 128, 0, stream>>>(b_gat, W_fus, b_fus, bfus2);
    hipMemsetAsync(degs, 0, (size_t)total * 4, stream);
    count_kernel<<<(E + 255) / 256, 256, 0, stream>>>(rowp, colp, degs, E, N);
    scan_reduce<<<P, 256, 0, stream>>>(degs, part, total);
    scan_partials<<<1, 64, 0, stream>>>(part, P);
    scan_write<<<P, 256, 0, stream>>>(degs, part, row_ptr, cursor, dinv, total, N);
    fill_kernel<<<(E + 255) / 256, 256, 0, stream>>>(rowp, colp, cursor, adj, E, N);

    // --- h = x @ W_emb^T + b_emb ---
    gemm128<false><<<(N + 31) / 32, 256, 0, stream>>>(x, W_emb, 128, 0, b_emb, B_h, N);

    // --- E8: gather + linear ---
    e8_gather<<<(N + 3) / 4, 256, 0, stream>>>(row_ptr, degs, adj, dinv, B_h, B_agg, N);
    gemm128<false><<<(N + 31) / 32, 256, 0, stream>>>(B_agg, W_e8, 128, 0, nullptr, B_e8, N);

    // --- GAT ---
    gemm128<false><<<(N + 31) / 32, 256, 0, stream>>>(B_h, W_gat, 128, 0, nullptr, B_g, N);
    att_kernel<<<(4 * N + 255) / 256, 256, 0, stream>>>(B_g, att_s, att_d, a_src, a_dst, N);
    gat_gather<<<(N + 3) / 4, 256, 0, stream>>>(row_ptr, degs, adj, a_src, a_dst, B_g, B_agg, N);

    // --- fusion: f = x_e8 @ Wf[:, :128]^T + bfus2 ; f += x_gat @ Wf[:,128:]^T ---
    gemm128<false><<<(N + 31) / 32, 256, 0, stream>>>(B_e8, W_fus, 256, 0, bfus2, B_g, N);
    gemm128<true><<<(N + 31) / 32, 256, 0, stream>>>(B_agg, W_fus, 256, 128, nullptr, B_g, N);

    // --- residual + LayerNorm + ReLU -> z (reuse B_e8) ---
    ln_kernel<<<N, 128, 0, stream>>>(B_g, B_h, gamma, beta, B_e8, N);

    // --- readout ---
    readout_kernel<<<(N + 3) / 4, 256, 0, stream>>>(B_e8, W_r1, b_r1, W_r2, b_r2,
                                                    (float*)d_out, N);
}

// Round 5
// 1571.756 us; speedup vs baseline: 1.8760x; 1.2979x over previous
//
#include <hip/hip_runtime.h>
#include <hip/hip_bf16.h>
#include <math.h>

#define SCAN_TILE 1024

// ---------------- prep: fold b_gat into fusion bias ----------------
__global__ void prep_kernel(const float* __restrict__ b_gat,
                            const float* __restrict__ W_fus, const float* __restrict__ b_fus,
                            float* __restrict__ bfus2) {
    int t = threadIdx.x;  // 128
    float acc = b_fus[t];
    for (int k = 0; k < 128; k++)
        acc += b_gat[k] * W_fus[t * 256 + 128 + k];
    bfus2[t] = acc;
}

// ---------------- CSR build: count ----------------
__global__ void count_kernel(const int* __restrict__ row, const int* __restrict__ col,
                             int* __restrict__ degs, int E, int N) {
    int e = blockIdx.x * 256 + threadIdx.x;
    if (e >= E) return;
    atomicAdd(&degs[col[e]], 1);       // dst counts (== reference deg)
    atomicAdd(&degs[N + row[e]], 1);   // src counts
}

// ---------------- CSR build: scan (3 kernels) ----------------
__global__ void scan_reduce(const int* __restrict__ degs, int* __restrict__ part, int total) {
    int b = blockIdx.x, t = threadIdx.x;  // 256 threads
    int base = b * SCAN_TILE + t * 4;
    int s = 0;
#pragma unroll
    for (int j = 0; j < 4; j++) { int i = base + j; if (i < total) s += degs[i]; }
    __shared__ int red[256];
    red[t] = s; __syncthreads();
    for (int st = 128; st > 0; st >>= 1) {
        if (t < st) red[t] += red[t + st];
        __syncthreads();
    }
    if (t == 0) part[b] = red[0];
}

__global__ void scan_partials(int* __restrict__ part, int P) {
    if (threadIdx.x == 0) {
        int run = 0;
        for (int i = 0; i < P; i++) { int v = part[i]; part[i] = run; run += v; }
    }
}

__global__ void scan_write(const int* __restrict__ degs, const int* __restrict__ part,
                           int* __restrict__ row_ptr, int* __restrict__ cursor,
                           float* __restrict__ dinv, int total, int N) {
    int b = blockIdx.x, t = threadIdx.x;  // 256
    int base = b * SCAN_TILE + t * 4;
    int v[4]; int s = 0;
#pragma unroll
    for (int j = 0; j < 4; j++) { int i = base + j; v[j] = (i < total) ? degs[i] : 0; s += v[j]; }
    __shared__ int bufA[256], bufB[256];
    bufA[t] = s; __syncthreads();
    int* src = bufA; int* dst = bufB;
    for (int off = 1; off < 256; off <<= 1) {
        int x = src[t];
        if (t >= off) x += src[t - off];
        dst[t] = x; __syncthreads();
        int* tp = src; src = dst; dst = tp;
    }
    int excl = src[t] - s;
    int run = part[b] + excl;
#pragma unroll
    for (int j = 0; j < 4; j++) {
        int i = base + j;
        if (i < total) {
            row_ptr[i] = run;
            cursor[i] = run;
            if (i < N) dinv[i] = v[j] > 0 ? rsqrtf((float)v[j]) : 0.0f;
            run += v[j];
        }
    }
}

// ---------------- CSR build: fill ----------------
__global__ void fill_kernel(const int* __restrict__ row, const int* __restrict__ col,
                            int* __restrict__ cursor, int* __restrict__ adj, int E, int N) {
    int e = blockIdx.x * 256 + threadIdx.x;
    if (e >= E) return;
    int r = row[e], c = col[e];
    int p1 = atomicAdd(&cursor[c], 1);      adj[p1] = r;  // dst-CSR: stores src
    int p2 = atomicAdd(&cursor[N + r], 1);  adj[p2] = c;  // src-CSR: stores dst
}

// ------- GEMM: C[n,128] = A[n,128] @ W[:, off:off+128]^T (+bias) (+=) -------
template <bool ACCUM>
__global__ __launch_bounds__(256) void gemm128(
    const float* __restrict__ A, const float* __restrict__ W,
    int w_stride, int w_off, const float* __restrict__ bias,
    float* __restrict__ C, int n) {
    __shared__ float Alds[32 * 132];
    __shared__ float Wlds[32 * 128];
    const int t = threadIdx.x;
    const int row0 = blockIdx.x * 32;

    for (int i = 0; i < 16; i++) {
        int idx = i * 256 + t;
        int r = idx >> 7, k = idx & 127;
        int row = row0 + r;
        Alds[r * 132 + k] = (row < n) ? A[(size_t)row * 128 + k] : 0.f;
    }

    const int rg = t >> 5, cg = t & 31;
    float acc[4][4] = {};

    for (int kt = 0; kt < 4; kt++) {
        __syncthreads();
        for (int i = 0; i < 16; i++) {
            int idx = i * 256 + t;
            int kk = idx >> 7, o = idx & 127;
            Wlds[kk * 128 + o] = W[o * w_stride + w_off + kt * 32 + kk];
        }
        __syncthreads();

        const float* Ab = &Alds[(rg * 4) * 132 + kt * 32];
        for (int k4 = 0; k4 < 8; k4++) {
            float4 av0 = *(const float4*)&Ab[0 * 132 + k4 * 4];
            float4 av1 = *(const float4*)&Ab[1 * 132 + k4 * 4];
            float4 av2 = *(const float4*)&Ab[2 * 132 + k4 * 4];
            float4 av3 = *(const float4*)&Ab[3 * 132 + k4 * 4];
            float a_[4][4] = {{av0.x, av0.y, av0.z, av0.w},
                              {av1.x, av1.y, av1.z, av1.w},
                              {av2.x, av2.y, av2.z, av2.w},
                              {av3.x, av3.y, av3.z, av3.w}};
#pragma unroll
            for (int kk = 0; kk < 4; kk++) {
                float4 wv = *(const float4*)&Wlds[(k4 * 4 + kk) * 128 + cg * 4];
#pragma unroll
                for (int r = 0; r < 4; r++) {
                    float a = a_[r][kk];
                    acc[r][0] += a * wv.x;
                    acc[r][1] += a * wv.y;
                    acc[r][2] += a * wv.z;
                    acc[r][3] += a * wv.w;
                }
            }
        }
    }
#pragma unroll
    for (int r = 0; r < 4; r++) {
        int row = row0 + rg * 4 + r;
        if (row >= n) continue;
        float4 o;
        o.x = acc[r][0]; o.y = acc[r][1]; o.z = acc[r][2]; o.w = acc[r][3];
        if (bias) {
            o.x += bias[cg * 4 + 0]; o.y += bias[cg * 4 + 1];
            o.z += bias[cg * 4 + 2]; o.w += bias[cg * 4 + 3];
        }
        float* cp = &C[(size_t)row * 128 + cg * 4];
        if (ACCUM) {
            float4 old = *(const float4*)cp;
            o.x += old.x; o.y += old.y; o.z += old.z; o.w += old.w;
        }
        *(float4*)cp = o;
    }
}

// ------- E8 gather: agg[r] = dinv[r] * sum_{c in srcCSR[r]} h[c]*dinv[c] -------
__global__ __launch_bounds__(256) void e8_gather(
    const int* __restrict__ row_ptr, const int* __restrict__ degs,
    const int* __restrict__ adj, const float* __restrict__ dinv,
    const float* __restrict__ h, float* __restrict__ agg, int N) {
    int r = blockIdx.x * 4 + (threadIdx.x >> 6);
    int lane = threadIdx.x & 63;
    if (r >= N) return;
    int start = row_ptr[N + r], cnt = degs[N + r];
    float ax = 0.f, ay = 0.f;
    for (int base = 0; base < cnt; base += 64) {
        int m = cnt - base; if (m > 64) m = 64;
        int av = (base + lane < cnt) ? adj[start + base + lane] : 0;
        int j = 0;
        for (; j + 4 <= m; j += 4) {
            int c0 = __shfl(av, j), c1 = __shfl(av, j + 1);
            int c2 = __shfl(av, j + 2), c3 = __shfl(av, j + 3);
            float v0 = dinv[c0], v1 = dinv[c1], v2 = dinv[c2], v3 = dinv[c3];
            float2 h0 = *(const float2*)&h[(size_t)c0 * 128 + lane * 2];
            float2 h1 = *(const float2*)&h[(size_t)c1 * 128 + lane * 2];
            float2 h2 = *(const float2*)&h[(size_t)c2 * 128 + lane * 2];
            float2 h3 = *(const float2*)&h[(size_t)c3 * 128 + lane * 2];
            ax += h0.x * v0 + h1.x * v1 + h2.x * v2 + h3.x * v3;
            ay += h0.y * v0 + h1.y * v1 + h2.y * v2 + h3.y * v3;
        }
        for (; j < m; j++) {
            int c = __shfl(av, j);
            float vc = dinv[c];
            float2 hv = *(const float2*)&h[(size_t)c * 128 + lane * 2];
            ax += hv.x * vc;
            ay += hv.y * vc;
        }
    }
    float dr = dinv[r];
    *(float2*)&agg[(size_t)r * 128 + lane * 2] = make_float2(ax * dr, ay * dr);
}

// ---------------- attention coefficients ----------------
__global__ void att_kernel(const float* __restrict__ g, const float* __restrict__ att_src,
                           const float* __restrict__ att_dst,
                           float* __restrict__ a_src, float* __restrict__ a_dst, int N) {
    int tid = blockIdx.x * 256 + threadIdx.x;
    if (tid >= N * 4) return;
    int n = tid >> 2, hd = tid & 3;
    const float* gr = &g[(size_t)n * 128 + hd * 32];
    const float* as = att_src + hd * 32;
    const float* ad = att_dst + hd * 32;
    float s = 0.f, d = 0.f;
    for (int c = 0; c < 32; c += 4) {
        float4 gv = *(const float4*)&gr[c];
        float4 sv = *(const float4*)&as[c];
        float4 dv = *(const float4*)&ad[c];
        s += gv.x * sv.x + gv.y * sv.y + gv.z * sv.z + gv.w * sv.w;
        d += gv.x * dv.x + gv.y * dv.y + gv.z * dv.z + gv.w * dv.w;
    }
    a_src[tid] = s;
    a_dst[tid] = d;
}

// ------- GAT fused: online softmax over dst-CSR (+implicit self-loop) -------
// lane owns features [2*lane, 2*lane+1], both in head (lane>>4)
__global__ __launch_bounds__(256) void gat_gather(
    const int* __restrict__ row_ptr, const int* __restrict__ degs,
    const int* __restrict__ adj, const float* __restrict__ a_src,
    const float* __restrict__ a_dst, const float* __restrict__ g,
    float* __restrict__ xg, int N) {
    int d = blockIdx.x * 4 + (threadIdx.x >> 6);
    int lane = threadIdx.x & 63;
    if (d >= N) return;
    int hd = lane >> 4;
    float ad = a_dst[d * 4 + hd];

    // self-loop seeds the online softmax
    float e = a_src[d * 4 + hd] + ad; e = e > 0.f ? e : 0.2f * e;
    float m0 = e, l = 1.f;
    float2 acc = *(const float2*)&g[(size_t)d * 128 + lane * 2];

    int start = row_ptr[d], cnt = degs[d];
    for (int base = 0; base < cnt; base += 64) {
        int mm = cnt - base; if (mm > 64) mm = 64;
        int av = (base + lane < cnt) ? adj[start + base + lane] : 0;
        int j = 0;
        for (; j + 2 <= mm; j += 2) {
            int s0 = __shfl(av, j), s1 = __shfl(av, j + 1);
            float t0 = a_src[s0 * 4 + hd] + ad; t0 = t0 > 0.f ? t0 : 0.2f * t0;
            float t1 = a_src[s1 * 4 + hd] + ad; t1 = t1 > 0.f ? t1 : 0.2f * t1;
            float2 g0 = *(const float2*)&g[(size_t)s0 * 128 + lane * 2];
            float2 g1 = *(const float2*)&g[(size_t)s1 * 128 + lane * 2];
            float mn = fmaxf(m0, fmaxf(t0, t1));
            float sc = __expf(m0 - mn), w0 = __expf(t0 - mn), w1 = __expf(t1 - mn);
            acc.x = acc.x * sc + w0 * g0.x + w1 * g1.x;
            acc.y = acc.y * sc + w0 * g0.y + w1 * g1.y;
            l = l * sc + w0 + w1;
            m0 = mn;
        }
        for (; j < mm; j++) {
            int s = __shfl(av, j);
            float t0 = a_src[s * 4 + hd] + ad; t0 = t0 > 0.f ? t0 : 0.2f * t0;
            float2 gv = *(const float2*)&g[(size_t)s * 128 + lane * 2];
            float mn = fmaxf(m0, t0);
            float sc = __expf(m0 - mn), w = __expf(t0 - mn);
            acc.x = acc.x * sc + w * gv.x;
            acc.y = acc.y * sc + w * gv.y;
            l = l * sc + w;
            m0 = mn;
        }
    }
    float inv = 1.f / l;
    *(float2*)&xg[(size_t)d * 128 + lane * 2] = make_float2(acc.x * inv, acc.y * inv);
}

// ---------------- fusion residual + LayerNorm + ReLU ----------------
__global__ __launch_bounds__(128) void ln_kernel(
    const float* __restrict__ f, const float* __restrict__ h,
    const float* __restrict__ gamma, const float* __restrict__ beta,
    float* __restrict__ z, int N) {
    __shared__ float red[128];
    __shared__ float red2[128];
    int nidx = blockIdx.x;
    int t = threadIdx.x;
    float v = f[(size_t)nidx * 128 + t] + h[(size_t)nidx * 128 + t];
    red[t] = v;
    red2[t] = v * v;
    __syncthreads();
    for (int s = 64; s > 0; s >>= 1) {
        if (t < s) { red[t] += red[t + s]; red2[t] += red2[t + s]; }
        __syncthreads();
    }
    float mu = red[0] * (1.f / 128.f);
    float var = red2[0] * (1.f / 128.f) - mu * mu;
    float inv = rsqrtf(var + 1e-5f);
    float zz = (v - mu) * inv * gamma[t] + beta[t];
    z[(size_t)nidx * 128 + t] = zz > 0.f ? zz : 0.f;
}

// --------- readout: r = relu(z@W1^T+b1); out = sigmoid(r@W2+b2) — LDS GEMM ---------
__global__ __launch_bounds__(256) void readout_kernel(
    const float* __restrict__ z, const float* __restrict__ W1, const float* __restrict__ b1,
    const float* __restrict__ W2, const float* __restrict__ b2,
    float* __restrict__ out, int N) {
    __shared__ float zs[32 * 132];
    __shared__ float wlds[64 * 132];
    __shared__ float w2s[64];
    __shared__ float b1s[64];
    const int t = threadIdx.x;
    const int row0 = blockIdx.x * 32;

    for (int i = 0; i < 4; i++) {          // 1024 float4 of z tile
        int idx = i * 256 + t;
        int r = idx >> 5, c4 = idx & 31;
        float4 v = make_float4(0.f, 0.f, 0.f, 0.f);
        if (row0 + r < N) v = *(const float4*)&z[(size_t)(row0 + r) * 128 + c4 * 4];
        *(float4*)&zs[r * 132 + c4 * 4] = v;
    }
    for (int i = 0; i < 8; i++) {          // 2048 float4 of W1
        int idx = i * 256 + t;
        int o = idx >> 5, c4 = idx & 31;
        *(float4*)&wlds[o * 132 + c4 * 4] = *(const float4*)&W1[o * 128 + c4 * 4];
    }
    if (t < 64) { w2s[t] = W2[t]; b1s[t] = b1[t]; }
    __syncthreads();

    const int rg = t >> 4;   // 16 groups x 2 rows
    const int cg = t & 15;   // 16 groups x 4 cols
    float acc[2][4] = {};
    const float* z0 = &zs[(rg * 2) * 132];
    const float* z1 = z0 + 132;
    for (int k4 = 0; k4 < 32; k4++) {
        float4 a0 = *(const float4*)&z0[k4 * 4];
        float4 a1 = *(const float4*)&z1[k4 * 4];
#pragma unroll
        for (int j = 0; j < 4; j++) {
            float4 wv = *(const float4*)&wlds[(cg * 4 + j) * 132 + k4 * 4];
            acc[0][j] += a0.x * wv.x + a0.y * wv.y + a0.z * wv.z + a0.w * wv.w;
            acc[1][j] += a1.x * wv.x + a1.y * wv.y + a1.z * wv.z + a1.w * wv.w;
        }
    }
    float p0 = 0.f, p1 = 0.f;
#pragma unroll
    for (int j = 0; j < 4; j++) {
        int o = cg * 4 + j;
        float r0 = acc[0][j] + b1s[o]; r0 = r0 > 0.f ? r0 : 0.f;
        float r1 = acc[1][j] + b1s[o]; r1 = r1 > 0.f ? r1 : 0.f;
        p0 += r0 * w2s[o]; p1 += r1 * w2s[o];
    }
    for (int off = 8; off > 0; off >>= 1) {
        p0 += __shfl_down(p0, off, 16);
        p1 += __shfl_down(p1, off, 16);
    }
    if (cg == 0) {
        float bb = b2[0];
        int r0i = row0 + rg * 2, r1i = r0i + 1;
        if (r0i < N) out[r0i] = 1.f / (1.f + __expf(-(p0 + bb)));
        if (r1i < N) out[r1i] = 1.f / (1.f + __expf(-(p1 + bb)));
    }
}

extern "C" void kernel_launch(void* const* d_in, const int* in_sizes, int n_in,
                              void* d_out, int out_size, void* d_ws, size_t ws_size,
                              hipStream_t stream) {
    const float* x     = (const float*)d_in[0];
    const int*   ei    = (const int*)d_in[1];
    const float* W_emb = (const float*)d_in[2];
    const float* b_emb = (const float*)d_in[3];
    const float* W_e8  = (const float*)d_in[4];
    const float* W_gat = (const float*)d_in[5];
    const float* att_s = (const float*)d_in[6];
    const float* att_d = (const float*)d_in[7];
    const float* b_gat = (const float*)d_in[8];
    const float* W_fus = (const float*)d_in[9];
    const float* b_fus = (const float*)d_in[10];
    const float* gamma = (const float*)d_in[11];
    const float* beta  = (const float*)d_in[12];
    const float* W_r1  = (const float*)d_in[13];
    const float* b_r1  = (const float*)d_in[14];
    const float* W_r2  = (const float*)d_in[15];
    const float* b_r2  = (const float*)d_in[16];

    const int N = in_sizes[0] / 128;
    const int E = in_sizes[1] / 2;
    const int* rowp = ei;
    const int* colp = ei + E;
    const int total = 2 * N;
    const int P = (total + SCAN_TILE - 1) / SCAN_TILE;

    const size_t NF = (size_t)N * 128;
    float* ws = (float*)d_ws;
    float* B_h   = ws;            // h (residual), live until LN
    float* B_agg = B_h + NF;      // e8 agg, then x_gat
    float* B_e8  = B_agg + NF;    // x_e8, then z
    float* B_g   = B_e8 + NF;     // g, then f
    float* dinv  = B_g + NF;
    float* a_src = dinv + N;
    float* a_dst = a_src + (size_t)4 * N;
    float* bfus2 = a_dst + (size_t)4 * N;
    int* degs    = (int*)(bfus2 + 128);
    int* row_ptr = degs + total;
    int* cursor  = row_ptr + total;
    int* part    = cursor + total;
    int* adj     = part + 1024;       // 2E ints

    // --- prep + CSR build ---
    prep_kernel<<<1, 128, 0, stream>>>(b_gat, W_fus, b_fus, bfus2);
    hipMemsetAsync(degs, 0, (size_t)total * 4, stream);
    count_kernel<<<(E + 255) / 256, 256, 0, stream>>>(rowp, colp, degs, E, N);
    scan_reduce<<<P, 256, 0, stream>>>(degs, part, total);
    scan_partials<<<1, 64, 0, stream>>>(part, P);
    scan_write<<<P, 256, 0, stream>>>(degs, part, row_ptr, cursor, dinv, total, N);
    fill_kernel<<<(E + 255) / 256, 256, 0, stream>>>(rowp, colp, cursor, adj, E, N);

    // --- h = x @ W_emb^T + b_emb ---
    gemm128<false><<<(N + 31) / 32, 256, 0, stream>>>(x, W_emb, 128, 0, b_emb, B_h, N);

    // --- E8: gather + linear ---
    e8_gather<<<(N + 3) / 4, 256, 0, stream>>>(row_ptr, degs, adj, dinv, B_h, B_agg, N);
    gemm128<false><<<(N + 31) / 32, 256, 0, stream>>>(B_agg, W_e8, 128, 0, nullptr, B_e8, N);

    // --- GAT ---
    gemm128<false><<<(N + 31) / 32, 256, 0, stream>>>(B_h, W_gat, 128, 0, nullptr, B_g, N);
    att_kernel<<<(4 * N + 255) / 256, 256, 0, stream>>>(B_g, att_s, att_d, a_src, a_dst, N);
    gat_gather<<<(N + 3) / 4, 256, 0, stream>>>(row_ptr, degs, adj, a_src, a_dst, B_g, B_agg, N);

    // --- fusion: f = x_e8 @ Wf[:, :128]^T + bfus2 ; f += x_gat @ Wf[:,128:]^T ---
    gemm128<false><<<(N + 31) / 32, 256, 0, stream>>>(B_e8, W_fus, 256, 0, bfus2, B_g, N);
    gemm128<true><<<(N + 31) / 32, 256, 0, stream>>>(B_agg, W_fus, 256, 128, nullptr, B_g, N);

    // --- residual + LayerNorm + ReLU -> z (reuse B_e8) ---
    ln_kernel<<<N, 128, 0, stream>>>(B_g, B_h, gamma, beta, B_e8, N);

    // --- readout ---
    readout_kernel<<<(N + 31) / 32, 256, 0, stream>>>(B_e8, W_r1, b_r1, W_r2, b_r2,
                                                      (float*)d_out, N);
}